// Round 11
// baseline (52.441 us; speedup 1.0000x reference)
//
#include <hip/hip_runtime.h>
#include <hip/hip_bf16.h>
#include <stdint.h>

#define BB 32
#define NN 1024
#define MM 1024
#define DD 256

typedef __attribute__((ext_vector_type(8))) short short8;
typedef __attribute__((ext_vector_type(4))) float floatx4;

__device__ inline unsigned short f2bf(float x) {
    union { __hip_bfloat16 h; unsigned short u; } cv;
    cv.h = __float2bfloat16(x);
    return cv.u;
}
__device__ inline short8 pack8(float4 a, float4 b) {
    short8 o;
    o[0] = f2bf(a.x); o[1] = f2bf(a.y); o[2] = f2bf(a.z); o[3] = f2bf(a.w);
    o[4] = f2bf(b.x); o[5] = f2bf(b.y); o[6] = f2bf(b.z); o[7] = f2bf(b.w);
    return o;
}
// async global->LDS. LDS dest = wave-uniform base; HW adds lane*size.
__device__ inline void async_copy16(void* lds, const void* g) {
    __builtin_amdgcn_global_load_lds(
        (const __attribute__((address_space(1))) unsigned int*)g,
        (__attribute__((address_space(3))) unsigned int*)lds, 16, 0, 0);
}

// ---------------------------------------------------------------------------
// Convert h2 only: fp32 -> bf16 + per-row sum of squares (fp32 exact).
// One wave per TWO rows (32 B/lane). 32768 rows -> 4096 blocks.
// ---------------------------------------------------------------------------
__global__ __launch_bounds__(256) void convert_kernel(
        const float* __restrict__ h2, unsigned short* __restrict__ h2b,
        float* __restrict__ sq2) {
    int wid  = blockIdx.x * 4 + (threadIdx.x >> 6);
    int lane = threadIdx.x & 63;
    int l5   = lane & 31;
    int row  = wid * 2 + (lane >> 5);

    const float4* p = (const float4*)(h2 + (size_t)row * DD) + l5 * 2;
    float4 a = p[0], c = p[1];

    float s = a.x*a.x + a.y*a.y + a.z*a.z + a.w*a.w
            + c.x*c.x + c.y*c.y + c.z*c.z + c.w*c.w;
    #pragma unroll
    for (int off = 16; off; off >>= 1) s += __shfl_xor(s, off, 64);

    *(short8*)((char*)(h2b + (size_t)row * DD) + l5 * 16) = pack8(a, c);
    if (l5 == 0) sq2[row] = s;
}

// ---------------------------------------------------------------------------
// A-resident batched GEMM + fused Hausdorff. 64-row A-tile, 4 waves,
// 256 thr, 72.5 KB LDS -> 2 BLOCKS/CU (cross-block latency hiding).
// Grid (32 b, 16 n-tiles) = 512 blocks. Prologue: A 64x256 fp32 -> LDS ->
// af[4][8] bf16 regs + sq1 by-product (wave 0); A region becomes the
// ring-4 B buffer (16 KB chunks). r7-proven loop: ONE barrier/step,
// counted vmcnt (8/../4/0), stage(s+3) after barrier, setprio around
// MFMA, LDS-only per-mt epilogue, plain-stored outputs.
// ---------------------------------------------------------------------------
__global__ __launch_bounds__(256, 2) void gemm_kernel(
        const float* __restrict__ h1, const unsigned short* __restrict__ h2b,
        const float* __restrict__ sq2,
        unsigned int* __restrict__ rowmin, unsigned int* __restrict__ colpart) {
    __shared__ __align__(16) char pool[65536];   // A panel -> B ring (4x16KB)
    __shared__ __align__(16) float  sq1_s[64];
    __shared__ __align__(16) float  sq2_s[1024];
    __shared__ unsigned int cl_s[1024];
    __shared__ unsigned int rl_s[64];

    const int b    = blockIdx.x;      // batch; XCD = b%8
    const int tile = blockIdx.y;      // n-tile 0..15
    const int n0   = tile * 64;

    const int tid  = threadIdx.x;
    const int wave = tid >> 6;        // 0..3
    const int lane = tid & 63;
    const int wm   = wave * 32;       // wave m-origin within 128-m chunk

    const int krow = lane >> 4;   // 0..3
    const int rrow = lane & 15;   // 0..15
    const int rx   = rrow & 7;
    const int lrow = krow * 4;
    const int lcol = rrow;

    const char* Ag = (const char*)(h1 + ((size_t)b * NN + n0) * DD);  // 1KB rows
    const char* Bg = (const char*)(h2b + (size_t)b * MM * DD);        // 512B rows

    // LDS inits (plain ds ops, drained by prologue lgkm waits)
    cl_s[tid] = 0x7F800000u;       cl_s[tid + 256] = 0x7F800000u;
    cl_s[tid + 512] = 0x7F800000u; cl_s[tid + 768] = 0x7F800000u;
    if (tid < 64) rl_s[tid] = 0x7F800000u;

    // ---- prologue vmem: sq2 (1 copy) + A panel 64 KB (16 copies) ----
    async_copy16((char*)sq2_s + wave * 1024,
                 (const char*)(sq2 + b * MM) + wave * 1024 + lane * 16);
    #pragma unroll
    for (int t = 0; t < 16; ++t) {
        int r = t * 4 + wave;
        async_copy16(pool + r * 1024,
                     Ag + (size_t)r * 1024 + ((lane ^ (r & 7)) << 4));
    }
    asm volatile("s_waitcnt vmcnt(0) lgkmcnt(0)" ::: "memory");
    __builtin_amdgcn_s_barrier();
    __builtin_amdgcn_sched_barrier(0);

    // ---- A fp32 -> af bf16 regs; sq1 by-product (wave 0) ----
    short8 af[4][8];
    {
        float ssum[4] = {0.f, 0.f, 0.f, 0.f};
        #pragma unroll
        for (int i = 0; i < 4; ++i) {
            const char* rp = pool + (size_t)(i * 16 + rrow) * 1024;
            #pragma unroll
            for (int kq = 0; kq < 8; ++kq) {
                int u0 = kq * 8 + krow * 2;
                float4 f0 = *(const float4*)(rp + ((u0 ^ rx) << 4));
                float4 f1 = *(const float4*)(rp + (((u0 + 1) ^ rx) << 4));
                af[i][kq] = pack8(f0, f1);
                if (wave == 0)
                    ssum[i] += f0.x*f0.x + f0.y*f0.y + f0.z*f0.z + f0.w*f0.w
                             + f1.x*f1.x + f1.y*f1.y + f1.z*f1.z + f1.w*f1.w;
            }
        }
        if (wave == 0) {
            #pragma unroll
            for (int i = 0; i < 4; ++i) {
                float s = ssum[i];
                s += __shfl_xor(s, 16, 64);
                s += __shfl_xor(s, 32, 64);
                if (lane < 16) sq1_s[i * 16 + rrow] = s;
            }
        }
    }
    asm volatile("s_waitcnt lgkmcnt(0)" ::: "memory");
    __builtin_amdgcn_sched_barrier(0);
    __builtin_amdgcn_s_barrier();
    __builtin_amdgcn_sched_barrier(0);

    // ---- A region dead -> B ring. Chunk: [128m][64k] bf16 = 16 KB,
    //      16 sub-chunks of 1 KB (8 rows x 128 B), 4 per wave. ----
    const int rl  = lane >> 3;            // row within sub-chunk
    const int bcu = (lane & 7) ^ rl;      // inverse-swizzled src 16B unit
    #define STAGE(mt_, ks_, boff_)                                            \
        { _Pragma("unroll")                                                   \
          for (int c = 0; c < 4; ++c) {                                       \
            int ch_ = wave * 4 + c;                                           \
            async_copy16(pool + (boff_) + ch_ * 1024,                         \
                Bg + (size_t)((mt_) * 128 + ch_ * 8 + rl) * 512               \
                   + (size_t)(ks_) * 128 + (bcu << 4)); } }

    STAGE(0, 0, 0); STAGE(0, 1, 16384); STAGE(0, 2, 32768);

    float rmin[4][4];
    #pragma unroll
    for (int i = 0; i < 4; ++i)
        #pragma unroll
        for (int r = 0; r < 4; ++r) rmin[i][r] = 3.0e38f;

    // ---- main loop: 32 steps (8 mt x 4 ks); buf = ks; waits 8/../4/0 ----
    #pragma unroll 1
    for (int mt = 0; mt < 8; ++mt) {
        floatx4 acc[4][2] = {};

        #pragma unroll
        for (int ks = 0; ks < 4; ++ks) {
            if (mt == 7 && ks == 2)      { asm volatile("s_waitcnt vmcnt(4)" ::: "memory"); }
            else if (mt == 7 && ks == 3) { asm volatile("s_waitcnt vmcnt(0)" ::: "memory"); }
            else                         { asm volatile("s_waitcnt vmcnt(8)" ::: "memory"); }
            __builtin_amdgcn_s_barrier();
            __builtin_amdgcn_sched_barrier(0);

            // stage step s+3 into ring buf (s+3)%4
            if (ks == 0)          { STAGE(mt,     3, 49152); }
            else if (mt < 7) {
                if (ks == 1)      { STAGE(mt + 1, 0, 0);     }
                else if (ks == 2) { STAGE(mt + 1, 1, 16384); }
                else              { STAGE(mt + 1, 2, 32768); }
            }

            // compute step s from buf ks
            const char* Bb = pool + ks * 16384;
            __builtin_amdgcn_s_setprio(1);
            #pragma unroll
            for (int kk = 0; kk < 2; ++kk) {
                const int u = ((kk << 2) | krow) ^ rx;
                short8 bfv[2];
                #pragma unroll
                for (int j = 0; j < 2; ++j)
                    bfv[j] = *(const short8*)(Bb
                             + (size_t)(wm + j * 16 + rrow) * 128 + (u << 4));
                #pragma unroll
                for (int i = 0; i < 4; ++i)
                    #pragma unroll
                    for (int j = 0; j < 2; ++j)
                        acc[i][j] = __builtin_amdgcn_mfma_f32_16x16x32_bf16(
                            af[i][ks * 2 + kk], bfv[j], acc[i][j], 0, 0, 0);
            }
            __builtin_amdgcn_s_setprio(0);
        }

        // ---- per-mt epilogue (regs + LDS only; no vmem) ----
        float s2v0 = sq2_s[mt * 128 + wm + lcol];
        float s2v1 = sq2_s[mt * 128 + wm + 16 + lcol];

        float cmin0 = 3.0e38f, cmin1 = 3.0e38f;
        #pragma unroll
        for (int i = 0; i < 4; ++i) {
            float4 s1q = *(const float4*)(&sq1_s[i * 16 + lrow]);
            #pragma unroll
            for (int r = 0; r < 4; ++r) {
                float s1x = ((const float*)&s1q)[r];
                float d0 = fmaxf(s1x + s2v0 - 2.0f * acc[i][0][r], 0.0f);
                float d1 = fmaxf(s1x + s2v1 - 2.0f * acc[i][1][r], 0.0f);
                rmin[i][r] = fminf(rmin[i][r], fminf(d0, d1));
                cmin0 = fminf(cmin0, d0);
                cmin1 = fminf(cmin1, d1);
            }
        }
        cmin0 = fminf(cmin0, __shfl_xor(cmin0, 16, 64));
        cmin0 = fminf(cmin0, __shfl_xor(cmin0, 32, 64));
        cmin1 = fminf(cmin1, __shfl_xor(cmin1, 16, 64));
        cmin1 = fminf(cmin1, __shfl_xor(cmin1, 32, 64));
        if (lane < 16) {
            atomicMin(&cl_s[mt * 128 + wm + lcol],      __float_as_uint(cmin0));
            atomicMin(&cl_s[mt * 128 + wm + 16 + lcol], __float_as_uint(cmin1));
        }
    }

    // ---- rowmin combine across the 4 waves + plain stores ----
    #pragma unroll
    for (int i = 0; i < 4; ++i) {
        #pragma unroll
        for (int r = 0; r < 4; ++r) {
            float v = rmin[i][r];
            #pragma unroll
            for (int off = 1; off < 16; off <<= 1)
                v = fminf(v, __shfl_xor(v, off, 64));
            if (lcol == 0)
                atomicMin(&rl_s[i * 16 + lrow + r], __float_as_uint(v));
        }
    }
    __syncthreads();

    unsigned int* cp = colpart + ((size_t)b * 16 + tile) * 1024;
    cp[tid]       = cl_s[tid];
    cp[tid + 256] = cl_s[tid + 256];
    cp[tid + 512] = cl_s[tid + 512];
    cp[tid + 768] = cl_s[tid + 768];
    if (tid < 64) rowmin[b * NN + n0 + tid] = rl_s[tid];
    #undef STAGE
}

// ---------------------------------------------------------------------------
// out[b] = (sum_n rowmin + sum_m min over 16 tiles of colpart) / 1024
// ---------------------------------------------------------------------------
__global__ __launch_bounds__(256) void finalize_kernel(
        const unsigned int* __restrict__ rowmin,
        const unsigned int* __restrict__ colpart,
        float* __restrict__ out) {
    int b = blockIdx.x;
    int tid = threadIdx.x;
    float s = 0.0f;
    #pragma unroll
    for (int t = 0; t < 4; ++t) {
        int m = tid + t * 256;
        s += __uint_as_float(rowmin[b * NN + m]);
        unsigned int v = colpart[(size_t)b * 16384 + m];
        #pragma unroll
        for (int q = 1; q < 16; ++q)
            v = min(v, colpart[(size_t)b * 16384 + q * 1024 + m]);
        s += __uint_as_float(v);
    }
    #pragma unroll
    for (int off = 32; off; off >>= 1) s += __shfl_xor(s, off, 64);
    __shared__ float wsum[4];
    if ((tid & 63) == 0) wsum[tid >> 6] = s;
    __syncthreads();
    if (tid == 0) out[b] = (wsum[0] + wsum[1] + wsum[2] + wsum[3]) * (1.0f / 1024.0f);
}

// ---------------------------------------------------------------------------
extern "C" void kernel_launch(void* const* d_in, const int* in_sizes, int n_in,
                              void* d_out, int out_size, void* d_ws, size_t ws_size,
                              hipStream_t stream) {
    const float* h1 = (const float*)d_in[0];
    const float* h2 = (const float*)d_in[1];
    float* out = (float*)d_out;

    char* ws = (char*)d_ws;
    unsigned short* h2b = (unsigned short*)ws;                    // 16.8 MB
    float* sq2          = (float*)(ws + (size_t)BB * MM * DD * 2);
    unsigned int* rowmin  = (unsigned int*)(sq2 + BB * MM);       // 128 KB
    unsigned int* colpart = rowmin + BB * NN;                     // 2 MB

    hipLaunchKernelGGL(convert_kernel, dim3(4096), dim3(256), 0, stream,
                       h2, h2b, sq2);

    hipLaunchKernelGGL(gemm_kernel, dim3(BB, 16), dim3(256), 0, stream,
                       h1, h2b, sq2, rowmin, colpart);

    hipLaunchKernelGGL(finalize_kernel, dim3(BB), dim3(256), 0, stream,
                       rowmin, colpart, out);
}